// Round 4
// baseline (3947.782 us; speedup 1.0000x reference)
//
#include <hip/hip_runtime.h>

// ---------------------------------------------------------------------------
// GRU stack: 3 layers (H=256,128,64) over [B=128,T=512,F=128] + dense sigmoid.
// R2: U weights truly register-resident via AGPR pinning (asm "+a"), 4 waves
// 1/SIMD (512-reg budget). xg z/r staged to LDS via global_load_lds DMA
// (1-step prefetch, zero VGPR), h-gate xg reg ping-pong. One barrier/step
// (parity double-buffered LDS). bf16-packed h master state.
// ---------------------------------------------------------------------------

typedef __attribute__((ext_vector_type(8))) __bf16 bf16x8;
typedef __attribute__((ext_vector_type(4))) float f32x4;

#define DEVINL __device__ __forceinline__
#define LOG2E 1.44269504088896340736f

DEVINL unsigned short bfbits(float f) {
  __bf16 h = (__bf16)f;
  unsigned short u;
  __builtin_memcpy(&u, &h, 2);
  return u;
}
DEVINL unsigned int pkbf(float a, float b) {
  return (unsigned int)bfbits(a) | ((unsigned int)bfbits(b) << 16);
}
DEVINL float bflo(unsigned int u) { return __uint_as_float(u << 16); }
DEVINL float bfhi(unsigned int u) { return __uint_as_float(u & 0xffff0000u); }

DEVINL float sigm(float x) {
  return __builtin_amdgcn_rcpf(1.0f + __expf(-x));
}
DEVINL float sigm2(float y) {  // sigmoid(x), y = x*log2e
#if __has_builtin(__builtin_amdgcn_exp2f)
  float e = __builtin_amdgcn_exp2f(-y);
#else
  float e = exp2f(-y);
#endif
  return __builtin_amdgcn_rcpf(1.0f + e);
}

DEVINL f32x4 mfma16(bf16x8 a, bf16x8 b, f32x4 c) {
  return __builtin_amdgcn_mfma_f32_16x16x32_bf16(a, b, c, 0, 0, 0);
}
DEVINL bf16x8 ldfrag(const unsigned short* p) {
  return *reinterpret_cast<const bf16x8*>(p);
}
// pin a fragment into the AGPR file (opaque -> no remat, no reload)
#define PIN_A(x) asm volatile("" : "+a"(x))

// async global->LDS DMA, 16B per lane (dest = uniform base + lane*16)
DEVINL void dma16(const unsigned short* g, unsigned short* l) {
  __builtin_amdgcn_global_load_lds(
      (const __attribute__((address_space(1))) unsigned int*)g,
      (__attribute__((address_space(3))) unsigned int*)l, 16, 0, 0);
}

// ---------------------------------------------------------------------------
// Weight permute: src fp32 [K,N] -> bf16 B-fragments; cols < n_scaled
// prescaled by log2e. Fragment (ntile,ktile): lane l elem j =
// src[ktile*32 + (l>>4)*8 + j][ntile*16 + (l&15)].
// ---------------------------------------------------------------------------
__global__ void kperm(const float* __restrict__ src, unsigned short* __restrict__ dst,
                      int K, int N, int n_scaled) {
  int KT = K >> 5;
  int tile = blockIdx.x;
  int ntile = tile / KT, ktile = tile - ntile * KT;
  int l = threadIdx.x;
  int col = ntile * 16 + (l & 15);
  int krow = ktile * 32 + ((l >> 4) << 3);
  float sc = (col < n_scaled) ? LOG2E : 1.0f;
  unsigned short tmp[8];
#pragma unroll
  for (int j = 0; j < 8; ++j) tmp[j] = bfbits(src[(size_t)(krow + j) * N + col] * sc);
  uint4 v;
  v.x = (unsigned int)tmp[0] | ((unsigned int)tmp[1] << 16);
  v.y = (unsigned int)tmp[2] | ((unsigned int)tmp[3] << 16);
  v.z = (unsigned int)tmp[4] | ((unsigned int)tmp[5] << 16);
  v.w = (unsigned int)tmp[6] | ((unsigned int)tmp[7] << 16);
  *reinterpret_cast<uint4*>(dst + (size_t)(tile * 64 + l) * 8) = v;
}

// ---------------------------------------------------------------------------
// xg layout v2 (ushort units), per (bblk,t) block of NTAU*768 us:
//   zr region: tau chunk at tau*512 + l*8   : uint4/lane = {z01,z23,r01,r23}
//   hh region: at NTAU*512 + (tau>>1)*512 + l*8 + (tau&1)*4 : uint2 = {h01,h23}
// Values are bf16 with input(+recurrent for z/r) bias folded, sigmoid gates
// prescaled by log2e. Rows lr*4+j = batch, col tau*16+lc = hidden.
// ---------------------------------------------------------------------------
__global__ void __launch_bounds__(256) kxg1(const float* __restrict__ text,
                                            const unsigned short* __restrict__ W1p,
                                            const float* __restrict__ b1,
                                            unsigned short* __restrict__ xg1) {
  __shared__ __attribute__((aligned(16))) unsigned short alds[16 * 2184];
  const int bblk = blockIdx.x, tch = blockIdx.y;
  const int tid = threadIdx.x;
  {
    int tt = tid >> 4, kc = tid & 15;
#pragma unroll
    for (int b = 0; b < 16; ++b) {
      const float* p = text + ((size_t)((bblk * 16 + b) * 512 + tch * 16 + tt)) * 128 + kc * 8;
      float4 f0 = *reinterpret_cast<const float4*>(p);
      float4 f1 = *reinterpret_cast<const float4*>(p + 4);
      uint4 v;
      v.x = pkbf(f0.x, f0.y);
      v.y = pkbf(f0.z, f0.w);
      v.z = pkbf(f1.x, f1.y);
      v.w = pkbf(f1.z, f1.w);
      *reinterpret_cast<uint4*>(&alds[b * 2184 + tt * 136 + kc * 8]) = v;
    }
  }
  __syncthreads();
  const int w = tid >> 6, l = tid & 63, lr = l >> 4, lc = l & 15;
  for (int mtg = 0; mtg < 4; ++mtg) {
    bf16x8 a[4][4];
#pragma unroll
    for (int m4 = 0; m4 < 4; ++m4)
#pragma unroll
      for (int kt = 0; kt < 4; ++kt)
        a[m4][kt] = ldfrag(&alds[lc * 2184 + (mtg * 4 + m4) * 136 + kt * 32 + lr * 8]);
    size_t tbase[4];
#pragma unroll
    for (int m4 = 0; m4 < 4; ++m4)
      tbase[m4] = ((size_t)(bblk * 512 + tch * 16 + mtg * 4 + m4)) * 12288;
#pragma unroll
    for (int ti = 0; ti < 4; ++ti) {
      int tau = 4 * w + ti;
      int n = tau * 16 + lc;
      float bz = (b1[n] + b1[768 + n]) * LOG2E;
      float br = (b1[256 + n] + b1[768 + 256 + n]) * LOG2E;
      bf16x8 wz[4], wr[4];
#pragma unroll
      for (int kt = 0; kt < 4; ++kt) {
        wz[kt] = ldfrag(W1p + (size_t)(tau * 4 + kt) * 512 + l * 8);
        wr[kt] = ldfrag(W1p + (size_t)((16 + tau) * 4 + kt) * 512 + l * 8);
      }
#pragma unroll
      for (int m4 = 0; m4 < 4; ++m4) {
        f32x4 az = {0.f, 0.f, 0.f, 0.f}, ar = {0.f, 0.f, 0.f, 0.f};
#pragma unroll
        for (int kt = 0; kt < 4; ++kt) {
          az = mfma16(a[m4][kt], wz[kt], az);
          ar = mfma16(a[m4][kt], wr[kt], ar);
        }
        uint4 v;
        v.x = pkbf(az[0] + bz, az[1] + bz);
        v.y = pkbf(az[2] + bz, az[3] + bz);
        v.z = pkbf(ar[0] + br, ar[1] + br);
        v.w = pkbf(ar[2] + br, ar[3] + br);
        *reinterpret_cast<uint4*>(xg1 + tbase[m4] + tau * 512 + l * 8) = v;
      }
      float bhh = b1[512 + n] * LOG2E;
      bf16x8 wh[4];
#pragma unroll
      for (int kt = 0; kt < 4; ++kt)
        wh[kt] = ldfrag(W1p + (size_t)((32 + tau) * 4 + kt) * 512 + l * 8);
#pragma unroll
      for (int m4 = 0; m4 < 4; ++m4) {
        f32x4 ah = {0.f, 0.f, 0.f, 0.f};
#pragma unroll
        for (int kt = 0; kt < 4; ++kt) ah = mfma16(a[m4][kt], wh[kt], ah);
        uint2 hv;
        hv.x = pkbf(ah[0] + bhh, ah[1] + bhh);
        hv.y = pkbf(ah[2] + bhh, ah[3] + bhh);
        *reinterpret_cast<uint2*>(xg1 + tbase[m4] + 8192 + (tau >> 1) * 512 + l * 8 + (tau & 1) * 4) = hv;
      }
    }
  }
}

// ---------------------------------------------------------------------------
// Layer-1 recurrence: 8 blocks x 256 thr (4 waves, 1/SIMD). Wave owns taus
// {4w..4w+3}; all 96 U-fragments AGPR-pinned. zr xg staged via DMA into LDS
// (prefetch t+1); h xg reg ping-pong; 1 barrier/step.
// ---------------------------------------------------------------------------
__global__ void __launch_bounds__(256, 1) kscan1(const unsigned short* __restrict__ xg1,
                                                 const unsigned short* __restrict__ U1p,
                                                 const float* __restrict__ b1,
                                                 unsigned short* __restrict__ seq1) {
  __shared__ __attribute__((aligned(16))) unsigned short h1b[2][16 * 264];
  __shared__ __attribute__((aligned(16))) unsigned short xst[2][8192];
  const int bblk = blockIdx.x;
  const int tid = threadIdx.x;
  const int w = tid >> 6, l = tid & 63, lr = l >> 4, lc = l & 15;
  const int tau0 = 4 * w;

  for (int i = tid; i < 16 * 264; i += 256) h1b[0][i] = 0;

  bf16x8 Bv[4][3][8];
#pragma unroll
  for (int ti = 0; ti < 4; ++ti)
#pragma unroll
    for (int g = 0; g < 3; ++g)
#pragma unroll
      for (int kt = 0; kt < 8; ++kt) {
        Bv[ti][g][kt] = ldfrag(U1p + (size_t)((g * 16 + (tau0 + ti)) * 8 + kt) * 512 + l * 8);
        PIN_A(Bv[ti][g][kt]);
      }

  float bh[4];
#pragma unroll
  for (int ti = 0; ti < 4; ++ti) bh[ti] = b1[768 + 512 + (tau0 + ti) * 16 + lc] * LOG2E;

  const unsigned short* pg = xg1 + (size_t)bblk * 512 * 12288;
  unsigned short* sq = seq1 + ((size_t)bblk * 16 + lr * 4) * 256 + lc;

  const f32x4 z4 = {0.f, 0.f, 0.f, 0.f};
  uint2 hs[4];
#pragma unroll
  for (int ti = 0; ti < 4; ++ti) hs[ti] = make_uint2(0u, 0u);

  uint2 UA[4], UB[4];

#define LOADU1(U, PP)                                                        \
  _Pragma("unroll") for (int ti = 0; ti < 4; ++ti)                           \
      U[ti] = *reinterpret_cast<const uint2*>(                               \
          (PP) + 8192 + ((tau0 + ti) >> 1) * 512 + l * 8 + ((tau0 + ti) & 1) * 4);

  // prologue: stage t=0
#pragma unroll
  for (int ti = 0; ti < 4; ++ti)
    dma16(pg + (tau0 + ti) * 512 + l * 8, &xst[0][(tau0 + ti) * 512]);
  LOADU1(UA, pg);
  __syncthreads();

#define STEP1(CUR, UC, UN, GUARD)                                                 \
  {                                                                               \
    bf16x8 a[8];                                                                  \
    _Pragma("unroll") for (int kt = 0; kt < 8; ++kt)                              \
        a[kt] = ldfrag(&h1b[CUR][lc * 264 + kt * 32 + lr * 8]);                   \
    if (GUARD) {                                                                  \
      _Pragma("unroll") for (int ti = 0; ti < 4; ++ti)                            \
          dma16(pg + 12288 + (tau0 + ti) * 512 + l * 8,                           \
                &xst[CUR ^ 1][(tau0 + ti) * 512]);                                \
      LOADU1(UN, pg + 12288);                                                     \
    }                                                                             \
    _Pragma("unroll") for (int ti = 0; ti < 4; ++ti) {                            \
      int tau = tau0 + ti;                                                        \
      uint4 qv = *reinterpret_cast<const uint4*>(&xst[CUR][tau * 512 + l * 8]);   \
      f32x4 az = z4, ar = z4, ah = z4;                                            \
      _Pragma("unroll") for (int kt = 0; kt < 8; ++kt) {                          \
        az = mfma16(a[kt], Bv[ti][0][kt], az);                                    \
        ar = mfma16(a[kt], Bv[ti][1][kt], ar);                                    \
        ah = mfma16(a[kt], Bv[ti][2][kt], ah);                                    \
      }                                                                           \
      float xzf[4] = {bflo(qv.x), bfhi(qv.x), bflo(qv.y), bfhi(qv.y)};            \
      float xrf[4] = {bflo(qv.z), bfhi(qv.z), bflo(qv.w), bfhi(qv.w)};            \
      float xhf[4] = {bflo(UC[ti].x), bfhi(UC[ti].x), bflo(UC[ti].y), bfhi(UC[ti].y)}; \
      float hn[4];                                                                \
      _Pragma("unroll") for (int j = 0; j < 4; ++j) {                             \
        float zz = sigm2(xzf[j] + az[j]);                                         \
        float rr = sigm2(xrf[j] + ar[j]);                                         \
        float hc = sigm2(__builtin_fmaf(rr, ah[j] + bh[ti], xhf[j]));             \
        float ho = (j & 1) ? bfhi(j < 2 ? hs[ti].x : hs[ti].y)                    \
                           : bflo(j < 2 ? hs[ti].x : hs[ti].y);                   \
        hn[j] = hc + zz * (ho - hc);                                              \
      }                                                                           \
      unsigned int p01 = pkbf(hn[0], hn[1]), p23 = pkbf(hn[2], hn[3]);            \
      hs[ti].x = p01;                                                             \
      hs[ti].y = p23;                                                             \
      unsigned short s0 = (unsigned short)p01, s1 = (unsigned short)(p01 >> 16);  \
      unsigned short s2 = (unsigned short)p23, s3 = (unsigned short)(p23 >> 16);  \
      h1b[CUR ^ 1][(lr * 4 + 0) * 264 + tau * 16 + lc] = s0;                      \
      h1b[CUR ^ 1][(lr * 4 + 1) * 264 + tau * 16 + lc] = s1;                      \
      h1b[CUR ^ 1][(lr * 4 + 2) * 264 + tau * 16 + lc] = s2;                      \
      h1b[CUR ^ 1][(lr * 4 + 3) * 264 + tau * 16 + lc] = s3;                      \
      sq[(size_t)0 * 256 + tau * 16] = s0;                                        \
      sq[(size_t)1 * 256 + tau * 16] = s1;                                        \
      sq[(size_t)2 * 256 + tau * 16] = s2;                                        \
      sq[(size_t)3 * 256 + tau * 16] = s3;                                        \
    }                                                                             \
    pg += 12288;                                                                  \
    sq += 32768;                                                                  \
    __syncthreads();                                                              \
  }

  for (int t = 0; t < 512; t += 2) {
    STEP1(0, UA, UB, true);
    STEP1(1, UB, UA, t + 2 < 512);
  }
#undef STEP1
#undef LOADU1
}

// ---------------------------------------------------------------------------
// xg2 = seq1 @ W2 (+ folded biases), v2 layout, NTAU=8, per-t block 6144 us.
// ---------------------------------------------------------------------------
__global__ void __launch_bounds__(256) kxg2(const unsigned short* __restrict__ seq1,
                                            const unsigned short* __restrict__ W2p,
                                            const float* __restrict__ b2,
                                            unsigned short* __restrict__ xg2) {
  const int bblk = blockIdx.x, tch = blockIdx.y;
  const int tid = threadIdx.x;
  const int w = tid >> 6, l = tid & 63, lr = l >> 4, lc = l & 15;
  for (int ttg = 0; ttg < 4; ++ttg) {
    bf16x8 a[4][8];
#pragma unroll
    for (int m4 = 0; m4 < 4; ++m4) {
      int tglob = tch * 16 + ttg * 4 + m4;
#pragma unroll
      for (int kt = 0; kt < 8; ++kt)
        a[m4][kt] = ldfrag(seq1 + (((size_t)tglob * 8 + bblk) * 16 + lc) * 256 + kt * 32 + lr * 8);
    }
    size_t tbase[4];
#pragma unroll
    for (int m4 = 0; m4 < 4; ++m4)
      tbase[m4] = ((size_t)(bblk * 512 + tch * 16 + ttg * 4 + m4)) * 6144;
#pragma unroll
    for (int ti = 0; ti < 2; ++ti) {
      int tau = 2 * w + ti;
      int n = tau * 16 + lc;
      float bz = (b2[n] + b2[384 + n]) * LOG2E;
      float br = (b2[128 + n] + b2[384 + 128 + n]) * LOG2E;
      bf16x8 wz[8], wr[8];
#pragma unroll
      for (int kt = 0; kt < 8; ++kt) {
        wz[kt] = ldfrag(W2p + (size_t)(tau * 8 + kt) * 512 + l * 8);
        wr[kt] = ldfrag(W2p + (size_t)((8 + tau) * 8 + kt) * 512 + l * 8);
      }
#pragma unroll
      for (int m4 = 0; m4 < 4; ++m4) {
        f32x4 az = {0.f, 0.f, 0.f, 0.f}, ar = {0.f, 0.f, 0.f, 0.f};
#pragma unroll
        for (int kt = 0; kt < 8; ++kt) {
          az = mfma16(a[m4][kt], wz[kt], az);
          ar = mfma16(a[m4][kt], wr[kt], ar);
        }
        uint4 v;
        v.x = pkbf(az[0] + bz, az[1] + bz);
        v.y = pkbf(az[2] + bz, az[3] + bz);
        v.z = pkbf(ar[0] + br, ar[1] + br);
        v.w = pkbf(ar[2] + br, ar[3] + br);
        *reinterpret_cast<uint4*>(xg2 + tbase[m4] + tau * 512 + l * 8) = v;
      }
      float bhh = b2[256 + n] * LOG2E;
      bf16x8 wh[8];
#pragma unroll
      for (int kt = 0; kt < 8; ++kt)
        wh[kt] = ldfrag(W2p + (size_t)((16 + tau) * 8 + kt) * 512 + l * 8);
#pragma unroll
      for (int m4 = 0; m4 < 4; ++m4) {
        f32x4 ah = {0.f, 0.f, 0.f, 0.f};
#pragma unroll
        for (int kt = 0; kt < 8; ++kt) ah = mfma16(a[m4][kt], wh[kt], ah);
        uint2 hv;
        hv.x = pkbf(ah[0] + bhh, ah[1] + bhh);
        hv.y = pkbf(ah[2] + bhh, ah[3] + bhh);
        *reinterpret_cast<uint2*>(xg2 + tbase[m4] + 4096 + (tau >> 1) * 512 + l * 8 + (tau & 1) * 4) = hv;
      }
    }
  }
}

// ---------------------------------------------------------------------------
// Layer-2 recurrence: 8 blocks x 256 thr (4 waves), wave owns taus {2w,2w+1}.
// ---------------------------------------------------------------------------
__global__ void __launch_bounds__(256, 1) kscan2(const unsigned short* __restrict__ xg2,
                                                 const unsigned short* __restrict__ U2p,
                                                 const float* __restrict__ b2,
                                                 unsigned short* __restrict__ seq2) {
  __shared__ __attribute__((aligned(16))) unsigned short h2b[2][16 * 136];
  __shared__ __attribute__((aligned(16))) unsigned short xst[2][4096];
  const int bblk = blockIdx.x;
  const int tid = threadIdx.x;
  const int w = tid >> 6, l = tid & 63, lr = l >> 4, lc = l & 15;
  const int tau0 = 2 * w;

  for (int i = tid; i < 16 * 136; i += 256) h2b[0][i] = 0;

  bf16x8 Bv[2][3][4];
#pragma unroll
  for (int ti = 0; ti < 2; ++ti)
#pragma unroll
    for (int g = 0; g < 3; ++g)
#pragma unroll
      for (int kt = 0; kt < 4; ++kt) {
        Bv[ti][g][kt] = ldfrag(U2p + (size_t)((g * 8 + (tau0 + ti)) * 4 + kt) * 512 + l * 8);
        PIN_A(Bv[ti][g][kt]);
      }

  float bh[2];
#pragma unroll
  for (int ti = 0; ti < 2; ++ti) bh[ti] = b2[384 + 256 + (tau0 + ti) * 16 + lc] * LOG2E;

  const unsigned short* pg = xg2 + (size_t)bblk * 512 * 6144;
  unsigned short* sq = seq2 + ((size_t)bblk * 16 + lr * 4) * 128 + lc;

  const f32x4 z4 = {0.f, 0.f, 0.f, 0.f};
  uint2 hs[2];
  hs[0] = make_uint2(0u, 0u);
  hs[1] = make_uint2(0u, 0u);
  uint2 UA[2], UB[2];

#define LOADU2(U, PP)                                                        \
  _Pragma("unroll") for (int ti = 0; ti < 2; ++ti)                           \
      U[ti] = *reinterpret_cast<const uint2*>(                               \
          (PP) + 4096 + w * 512 + l * 8 + ti * 4);

#pragma unroll
  for (int ti = 0; ti < 2; ++ti)
    dma16(pg + (tau0 + ti) * 512 + l * 8, &xst[0][(tau0 + ti) * 512]);
  LOADU2(UA, pg);
  __syncthreads();

#define STEP2(CUR, UC, UN, GUARD)                                                 \
  {                                                                               \
    bf16x8 a[4];                                                                  \
    _Pragma("unroll") for (int kt = 0; kt < 4; ++kt)                              \
        a[kt] = ldfrag(&h2b[CUR][lc * 136 + kt * 32 + lr * 8]);                   \
    if (GUARD) {                                                                  \
      _Pragma("unroll") for (int ti = 0; ti < 2; ++ti)                            \
          dma16(pg + 6144 + (tau0 + ti) * 512 + l * 8,                            \
                &xst[CUR ^ 1][(tau0 + ti) * 512]);                                \
      LOADU2(UN, pg + 6144);                                                      \
    }                                                                             \
    _Pragma("unroll") for (int ti = 0; ti < 2; ++ti) {                            \
      int tau = tau0 + ti;                                                        \
      uint4 qv = *reinterpret_cast<const uint4*>(&xst[CUR][tau * 512 + l * 8]);   \
      f32x4 az = z4, ar = z4, ah = z4;                                            \
      _Pragma("unroll") for (int kt = 0; kt < 4; ++kt) {                          \
        az = mfma16(a[kt], Bv[ti][0][kt], az);                                    \
        ar = mfma16(a[kt], Bv[ti][1][kt], ar);                                    \
        ah = mfma16(a[kt], Bv[ti][2][kt], ah);                                    \
      }                                                                           \
      float xzf[4] = {bflo(qv.x), bfhi(qv.x), bflo(qv.y), bfhi(qv.y)};            \
      float xrf[4] = {bflo(qv.z), bfhi(qv.z), bflo(qv.w), bfhi(qv.w)};            \
      float xhf[4] = {bflo(UC[ti].x), bfhi(UC[ti].x), bflo(UC[ti].y), bfhi(UC[ti].y)}; \
      float hn[4];                                                                \
      _Pragma("unroll") for (int j = 0; j < 4; ++j) {                             \
        float zz = sigm2(xzf[j] + az[j]);                                         \
        float rr = sigm2(xrf[j] + ar[j]);                                         \
        float hc = sigm2(__builtin_fmaf(rr, ah[j] + bh[ti], xhf[j]));             \
        float ho = (j & 1) ? bfhi(j < 2 ? hs[ti].x : hs[ti].y)                    \
                           : bflo(j < 2 ? hs[ti].x : hs[ti].y);                   \
        hn[j] = hc + zz * (ho - hc);                                              \
      }                                                                           \
      unsigned int p01 = pkbf(hn[0], hn[1]), p23 = pkbf(hn[2], hn[3]);            \
      hs[ti].x = p01;                                                             \
      hs[ti].y = p23;                                                             \
      unsigned short s0 = (unsigned short)p01, s1 = (unsigned short)(p01 >> 16);  \
      unsigned short s2 = (unsigned short)p23, s3 = (unsigned short)(p23 >> 16);  \
      h2b[CUR ^ 1][(lr * 4 + 0) * 136 + tau * 16 + lc] = s0;                      \
      h2b[CUR ^ 1][(lr * 4 + 1) * 136 + tau * 16 + lc] = s1;                      \
      h2b[CUR ^ 1][(lr * 4 + 2) * 136 + tau * 16 + lc] = s2;                      \
      h2b[CUR ^ 1][(lr * 4 + 3) * 136 + tau * 16 + lc] = s3;                      \
      sq[(size_t)0 * 128 + tau * 16] = s0;                                        \
      sq[(size_t)1 * 128 + tau * 16] = s1;                                        \
      sq[(size_t)2 * 128 + tau * 16] = s2;                                        \
      sq[(size_t)3 * 128 + tau * 16] = s3;                                        \
    }                                                                             \
    pg += 6144;                                                                   \
    sq += 16384;                                                                  \
    __syncthreads();                                                              \
  }

  for (int t = 0; t < 512; t += 2) {
    STEP2(0, UA, UB, true);
    STEP2(1, UB, UA, t + 2 < 512);
  }
#undef STEP2
#undef LOADU2
}

// ---------------------------------------------------------------------------
// xg3 = seq2 @ W3 (+ folded z/r biases; h unscaled), old tuple layout.
// ---------------------------------------------------------------------------
__global__ void __launch_bounds__(256) kxg3(const unsigned short* __restrict__ seq2,
                                            const unsigned short* __restrict__ W3p,
                                            const float* __restrict__ b3,
                                            unsigned short* __restrict__ xg3) {
  const int bblk = blockIdx.x, tch = blockIdx.y;
  const int tid = threadIdx.x;
  const int w = tid >> 6, l = tid & 63, lr = l >> 4, lc = l & 15;
  for (int ttg = 0; ttg < 4; ++ttg) {
    bf16x8 a[4][4];
#pragma unroll
    for (int m4 = 0; m4 < 4; ++m4) {
      int tglob = tch * 16 + ttg * 4 + m4;
#pragma unroll
      for (int kt = 0; kt < 4; ++kt)
        a[m4][kt] = ldfrag(seq2 + (((size_t)tglob * 8 + bblk) * 16 + lc) * 128 + kt * 32 + lr * 8);
    }
    for (int ni = 0; ni < 3; ++ni) {
      int nt = w * 3 + ni;  // 0..11
      bf16x8 bb[4];
#pragma unroll
      for (int kt = 0; kt < 4; ++kt)
        bb[kt] = ldfrag(W3p + (size_t)(nt * 4 + kt) * 512 + l * 8);
      int g = nt >> 2, tau = nt & 3;
      int n = nt * 16 + lc;
      float bias = b3[n] + ((g < 2) ? b3[192 + n] : 0.f);
      if (g < 2) bias *= LOG2E;
#pragma unroll
      for (int m4 = 0; m4 < 4; ++m4) {
        f32x4 acc = {0.f, 0.f, 0.f, 0.f};
#pragma unroll
        for (int kt = 0; kt < 4; ++kt) acc = mfma16(a[m4][kt], bb[kt], acc);
        int tglob = tch * 16 + ttg * 4 + m4;
        uint2 st;
        st.x = pkbf(acc[0] + bias, acc[1] + bias);
        st.y = pkbf(acc[2] + bias, acc[3] + bias);
        size_t base = ((((size_t)bblk * 512 + tglob) * 4 + tau) * 3 + g) * 256 + (size_t)l * 4;
        *reinterpret_cast<uint2*>(xg3 + base) = st;
      }
    }
  }
}

// ---------------------------------------------------------------------------
// Layer-3 recurrence (H3=64, relu candidate) + dense sigmoid head.
// 8 blocks x 256 thr (4 waves), tau = w. xg3 reg ping-pong, dbuf h3b.
// ---------------------------------------------------------------------------
__global__ void __launch_bounds__(256, 1) kscan3(const unsigned short* __restrict__ xg3,
                                                 const unsigned short* __restrict__ U3p,
                                                 const float* __restrict__ b3,
                                                 const float* __restrict__ Wo,
                                                 const float* __restrict__ bo,
                                                 float* __restrict__ out) {
  __shared__ __attribute__((aligned(16))) unsigned short h3b[2][16 * 72];
  __shared__ float h3s[16 * 68];
  const int bblk = blockIdx.x;
  const int tid = threadIdx.x;
  const int w = tid >> 6, l = tid & 63, lr = l >> 4, lc = l & 15;
  for (int i = tid; i < 16 * 72; i += 256) h3b[0][i] = 0;

  bf16x8 Bv[3][2];
#pragma unroll
  for (int g = 0; g < 3; ++g)
#pragma unroll
    for (int kt = 0; kt < 2; ++kt) {
      Bv[g][kt] = ldfrag(U3p + (size_t)((g * 4 + w) * 2 + kt) * 512 + l * 8);
      PIN_A(Bv[g][kt]);
    }

  const float bh = b3[192 + 128 + w * 16 + lc];  // raw (relu path)

  const unsigned short* p = xg3 + (size_t)bblk * 512 * 3072 + (size_t)w * 768 + l * 4;

  const f32x4 z4 = {0.f, 0.f, 0.f, 0.f};
  f32x4 hf = z4;
  uint2 AZ, AR, AH, BZ, BR, BH3;

  AZ = *reinterpret_cast<const uint2*>(p);
  AR = *reinterpret_cast<const uint2*>(p + 256);
  AH = *reinterpret_cast<const uint2*>(p + 512);
  __syncthreads();

#define STEP3(CUR, CZ, CR, CH, NZ, NR, NH, GUARD)                               \
  {                                                                             \
    bf16x8 a[2];                                                                \
    _Pragma("unroll") for (int kt = 0; kt < 2; ++kt)                            \
        a[kt] = ldfrag(&h3b[CUR][lc * 72 + kt * 32 + lr * 8]);                  \
    if (GUARD) {                                                                \
      NZ = *reinterpret_cast<const uint2*>(p + 3072);                           \
      NR = *reinterpret_cast<const uint2*>(p + 3072 + 256);                     \
      NH = *reinterpret_cast<const uint2*>(p + 3072 + 512);                     \
    }                                                                           \
    f32x4 az = z4, ar = z4, ah = z4;                                            \
    _Pragma("unroll") for (int kt = 0; kt < 2; ++kt) {                          \
      az = mfma16(a[kt], Bv[0][kt], az);                                        \
      ar = mfma16(a[kt], Bv[1][kt], ar);                                        \
      ah = mfma16(a[kt], Bv[2][kt], ah);                                        \
    }                                                                           \
    float xzf[4] = {bflo(CZ.x), bfhi(CZ.x), bflo(CZ.y), bfhi(CZ.y)};            \
    float xrf[4] = {bflo(CR.x), bfhi(CR.x), bflo(CR.y), bfhi(CR.y)};            \
    float xhf[4] = {bflo(CH.x), bfhi(CH.x), bflo(CH.y), bfhi(CH.y)};            \
    _Pragma("unroll") for (int j = 0; j < 4; ++j) {                             \
      float zz = sigm2(xzf[j] + az[j]);                                         \
      float rr = sigm2(xrf[j] + ar[j]);                                         \
      float hc = fmaxf(0.0f, __builtin_fmaf(rr, ah[j] + bh, xhf[j]));           \
      hf[j] = hc + zz * (hf[j] - hc);                                           \
    }                                                                           \
    _Pragma("unroll") for (int j = 0; j < 4; ++j)                               \
        h3b[CUR ^ 1][(lr * 4 + j) * 72 + w * 16 + lc] = bfbits(hf[j]);          \
    p += 3072;                                                                  \
    __syncthreads();                                                            \
  }

  for (int t = 0; t < 512; t += 2) {
    STEP3(0, AZ, AR, AH, BZ, BR, BH3, true);
    STEP3(1, BZ, BR, BH3, AZ, AR, AH, t + 2 < 512);
  }
#undef STEP3

  // dense head: out[b] = sigmoid(h3[b,:] . Wo + bo)
#pragma unroll
  for (int j = 0; j < 4; ++j)
    h3s[(lr * 4 + j) * 68 + w * 16 + lc] = hf[j];
  __syncthreads();
  if (tid < 16) {
    float s = bo[0];
    for (int n = 0; n < 64; ++n) s += h3s[tid * 68 + n] * Wo[n];
    out[bblk * 16 + tid] = sigm(s);
  }
}

// ---------------------------------------------------------------------------
extern "C" void kernel_launch(void* const* d_in, const int* in_sizes, int n_in,
                              void* d_out, int out_size, void* d_ws, size_t ws_size,
                              hipStream_t stream) {
  (void)in_sizes; (void)n_in; (void)out_size; (void)ws_size;
  const float* text = (const float*)d_in[0];
  const float* W1 = (const float*)d_in[1];
  const float* U1 = (const float*)d_in[2];
  const float* b1 = (const float*)d_in[3];
  const float* W2 = (const float*)d_in[4];
  const float* U2 = (const float*)d_in[5];
  const float* b2 = (const float*)d_in[6];
  const float* W3 = (const float*)d_in[7];
  const float* U3 = (const float*)d_in[8];
  const float* b3 = (const float*)d_in[9];
  const float* Wo = (const float*)d_in[10];
  const float* bo = (const float*)d_in[11];
  float* out = (float*)d_out;
  char* ws = (char*)d_ws;

  // workspace layout (ushort elements)
  unsigned short* W1p = (unsigned short*)ws;              // 98304
  unsigned short* U1p = W1p + 98304;                      // 196608
  unsigned short* W2p = U1p + 196608;                     // 98304
  unsigned short* U2p = W2p + 98304;                      // 49152
  unsigned short* W3p = U2p + 49152;                      // 24576
  unsigned short* U3p = W3p + 24576;                      // 12288
  unsigned short* big = (unsigned short*)(ws + 1048576);  // xg1 / xg2
  unsigned short* seq1 = big + 50331648;                  // 16777216 / xg3
  unsigned short* seq2 = seq1 + 16777216;                 // 8388608
  unsigned short* xg1 = big;
  unsigned short* xg2 = big;
  unsigned short* xg3 = seq1;

  kperm<<<192, 64, 0, stream>>>(W1, W1p, 128, 768, 768);
  kperm<<<384, 64, 0, stream>>>(U1, U1p, 256, 768, 768);
  kperm<<<192, 64, 0, stream>>>(W2, W2p, 256, 384, 384);
  kperm<<<96, 64, 0, stream>>>(U2, U2p, 128, 384, 384);
  kperm<<<48, 64, 0, stream>>>(W3, W3p, 128, 192, 128);
  kperm<<<24, 64, 0, stream>>>(U3, U3p, 64, 192, 128);

  kxg1<<<dim3(8, 32), 256, 0, stream>>>(text, W1p, b1, xg1);
  kscan1<<<8, 256, 0, stream>>>(xg1, U1p, b1, seq1);
  kxg2<<<dim3(8, 32), 256, 0, stream>>>(seq1, W2p, b2, xg2);
  kscan2<<<8, 256, 0, stream>>>(xg2, U2p, b2, seq2);
  kxg3<<<dim3(8, 32), 256, 0, stream>>>(seq2, W3p, b3, xg3);
  kscan3<<<8, 256, 0, stream>>>(xg3, U3p, b3, Wo, bo, out);
}